// Round 10
// baseline (387.641 us; speedup 1.0000x reference)
//
#include <hip/hip_runtime.h>
#include <cstdint>
#include <cstddef>

// GCN link prediction: 3x GCNConv(64->64) + ReLU, then 2-layer MLP head.
// N=100k, E=1M, dims 64. Round 10:
//  - Nontemporal ei loads in k_count/k_fill: the streamed edge list no longer
//    evicts partially-filled srcs lines from L2 (round-9 WRITE 41MB for 4MB
//    payload = eviction-driven rewrite amplification).
//  - Activations carried as hi/lo bf16 PLANES (split done once in producer
//    epilogues). mm kernels load MFMA A-fragments directly (16B loads, no
//    per-wave split VALU). hws gather table stays packed RNE bf16 rows.

#define CDIV(a, b) (((a) + (b) - 1) / (b))
static constexpr int SCAN_B = 1024;

typedef __attribute__((ext_vector_type(8))) short bf16x8;
typedef __attribute__((ext_vector_type(4))) float f32x4;

// Split a into hi (RNE bf16) + lo (truncated bf16 of exact residual).
__device__ __forceinline__ void split_bf(float a, short& hi, short& lo) {
  unsigned u = __float_as_uint(a);
  unsigned r = u + (0x7FFF + ((u >> 16) & 1));  // RNE round to bf16
  hi = (short)(r >> 16);
  float hirec = __uint_as_float(r & 0xFFFF0000u);
  float res = a - hirec;  // exact
  lo = (short)(__float_as_uint(res) >> 16);  // truncate
}

__device__ __forceinline__ unsigned short f2bf_rne(float a) {
  unsigned u = __float_as_uint(a);
  u += 0x7FFF + ((u >> 16) & 1);
  return (unsigned short)(u >> 16);
}

__device__ __forceinline__ float4 bf4_to_f4(uint2 u) {
  float4 v;
  v.x = __uint_as_float(u.x << 16);
  v.y = __uint_as_float(u.x & 0xFFFF0000u);
  v.z = __uint_as_float(u.y << 16);
  v.w = __uint_as_float(u.y & 0xFFFF0000u);
  return v;
}

__global__ void k_zero_i32(int* __restrict__ p, int n) {
  int i = blockIdx.x * blockDim.x + threadIdx.x;
  if (i < n) p[i] = 0;
}

__global__ void k_count(const int* __restrict__ ei, int* __restrict__ counts, int E) {
  int e = blockIdx.x * blockDim.x + threadIdx.x;
  if (e < E) {
    int d = __builtin_nontemporal_load(&ei[E + e]);
    atomicAdd(&counts[d], 1);
  }
}

// Inclusive block scan -> exclusive output + per-block sums; also dinv.
__global__ void k_scan1(const int* __restrict__ counts, int* __restrict__ excl,
                        int* __restrict__ bsums, float* __restrict__ dinv, int n) {
  __shared__ int sh[SCAN_B];
  int t = threadIdx.x;
  int idx = blockIdx.x * SCAN_B + t;
  int v = (idx < n) ? counts[idx] : 0;
  if (idx < n) dinv[idx] = rsqrtf((float)v + 1.0f);
  int val = v;
  sh[t] = val;
  __syncthreads();
  for (int off = 1; off < SCAN_B; off <<= 1) {
    int add = (t >= off) ? sh[t - off] : 0;
    __syncthreads();
    val += add;
    sh[t] = val;
    __syncthreads();
  }
  if (idx < n) excl[idx] = val - v;
  if (t == SCAN_B - 1) bsums[blockIdx.x] = val;
}

__global__ void k_scan2(int* __restrict__ bsums, int nb) {
  __shared__ int sh[SCAN_B];
  int t = threadIdx.x;
  int v = (t < nb) ? bsums[t] : 0;
  int val = v;
  sh[t] = val;
  __syncthreads();
  for (int off = 1; off < SCAN_B; off <<= 1) {
    int add = (t >= off) ? sh[t - off] : 0;
    __syncthreads();
    val += add;
    sh[t] = val;
    __syncthreads();
  }
  if (t < nb) bsums[t] = val - v;
}

// Finalize row_ptr; init fill cursors to row_ptr.
__global__ void k_scan3(int* __restrict__ row_ptr, const int* __restrict__ bsums,
                        int* __restrict__ cursors, int n, int E) {
  int i = blockIdx.x * blockDim.x + threadIdx.x;
  if (i < n) {
    int rp = row_ptr[i] + bsums[i >> 10];  // SCAN_B == 1024
    row_ptr[i] = rp;
    cursors[i] = rp;
  }
  if (i == 0) row_ptr[n] = E;
}

// XCD-grouped scatter (blockIdx%8 -> dst range); nontemporal ei reads so the
// 8 streaming sweeps don't evict partially-filled srcs lines from L2.
__global__ void k_fill(const int* __restrict__ ei, int* __restrict__ cursors,
                       int* __restrict__ srcs, int E, int N) {
  int g = blockIdx.x & 7;
  int bi = blockIdx.x >> 3;
  int stride = (gridDim.x >> 3) * blockDim.x;
  int lo = (int)(((long long)N * g) >> 3);
  int hi = (int)(((long long)N * (g + 1)) >> 3);
  for (int e = bi * blockDim.x + threadIdx.x; e < E; e += stride) {
    int d = __builtin_nontemporal_load(&ei[E + e]);
    if (d >= lo && d < hi) {
      int s = __builtin_nontemporal_load(&ei[e]);
      int pos = atomicAdd(&cursors[d], 1);
      srcs[pos] = s;
    }
  }
}

// Pre-split 5 weight matrices (64x64, [in,out] row-major) into hi/lo bf16
// fragments, packed: packed[mat*1024 + ((t*2+q)*2+h)*64 + lane].
__global__ void k_prep(const float* __restrict__ w0, const float* __restrict__ w1,
                       const float* __restrict__ w2, const float* __restrict__ w3,
                       const float* __restrict__ w4, bf16x8* __restrict__ packed) {
  const float* W;
  switch (blockIdx.x) {
    case 0: W = w0; break;
    case 1: W = w1; break;
    case 2: W = w2; break;
    case 3: W = w3; break;
    default: W = w4; break;
  }
  int tid = threadIdx.x;  // 0..511
  int lane = tid & 63;
  int q = (tid >> 6) & 1;
  int t = tid >> 7;
  int col = lane & 15, quad = lane >> 4;
  bf16x8 hi8, lo8;
#pragma unroll
  for (int j = 0; j < 8; ++j) {
    int k = q * 32 + quad * 8 + j;
    short hi, lo;
    split_bf(W[k * 64 + t * 16 + col], hi, lo);
    hi8[j] = hi;
    lo8[j] = lo;
  }
  size_t base = (size_t)blockIdx.x * 1024 + ((t * 2 + q) * 2) * 64 + lane;
  packed[base] = hi8;
  packed[base + 64] = lo8;
}

// C[n x 64] = A @ W (+bias) (+relu) (optionally *dinv[row]).
// A source: fp32 array (IN_PLANES=false, split on the fly) or hi/lo bf16
// planes (IN_PLANES=true, direct 16B fragment loads).
// OUT_MODE: 0 = fp32, 1 = packed RNE bf16 (gather table), 2 = hi/lo planes.
// In-place planes->planes is safe: each tile is read fully before its
// stores, and tiles are wave-disjoint.
// Verified layouts: A[m=lane&15][k=quad*8+j]; B[k][n=lane&15];
// C col=lane&15, row=quad*4+reg.
template <bool HAS_BIAS, bool RELU_OUT, bool DINV_OUT, bool IN_PLANES, int OUT_MODE>
__global__ __launch_bounds__(256, 4)
void k_mm(const float* __restrict__ inf, const unsigned short* __restrict__ ihp,
          const unsigned short* __restrict__ ilp, const bf16x8* __restrict__ Wp,
          const float* __restrict__ bias, const float* __restrict__ dinv,
          void* __restrict__ out0, void* __restrict__ out1, int n) {
  int lane = threadIdx.x & 63;
  int col = lane & 15, quad = lane >> 4;
  int tile = (blockIdx.x * blockDim.x + threadIdx.x) >> 6;
  int ntiles = (n + 15) >> 4;
  if (tile >= ntiles) return;

  bf16x8 wh[4][2], wl[4][2];
#pragma unroll
  for (int t = 0; t < 4; ++t)
#pragma unroll
    for (int q = 0; q < 2; ++q) {
      wh[t][q] = Wp[((t * 2 + q) * 2) * 64 + lane];
      wl[t][q] = Wp[((t * 2 + q) * 2 + 1) * 64 + lane];
    }
  float bv[4];
#pragma unroll
  for (int t = 0; t < 4; ++t) bv[t] = HAS_BIAS ? bias[t * 16 + col] : 0.0f;

  int row0 = tile << 4;
  int ar = row0 + col;
  if (ar > n - 1) ar = n - 1;  // clamp; stores guarded

  bf16x8 ah[2], al[2];
  if (IN_PLANES) {
#pragma unroll
    for (int q = 0; q < 2; ++q) {
      ah[q] = *(const bf16x8*)(ihp + (size_t)ar * 64 + q * 32 + quad * 8);
      al[q] = *(const bf16x8*)(ilp + (size_t)ar * 64 + q * 32 + quad * 8);
    }
  } else {
    const float4* arow = (const float4*)(inf + (size_t)ar * 64 + quad * 8);
    float4 a0 = arow[0], a1 = arow[1], a2 = arow[8], a3 = arow[9];
    float av0[8] = {a0.x, a0.y, a0.z, a0.w, a1.x, a1.y, a1.z, a1.w};
    float av1[8] = {a2.x, a2.y, a2.z, a2.w, a3.x, a3.y, a3.z, a3.w};
#pragma unroll
    for (int j = 0; j < 8; ++j) {
      short hi, lo;
      split_bf(av0[j], hi, lo);
      ah[0][j] = hi; al[0][j] = lo;
      split_bf(av1[j], hi, lo);
      ah[1][j] = hi; al[1][j] = lo;
    }
  }

  f32x4 acc[4];
#pragma unroll
  for (int t = 0; t < 4; ++t) acc[t] = (f32x4){0.f, 0.f, 0.f, 0.f};
#pragma unroll
  for (int t = 0; t < 4; ++t)
#pragma unroll
    for (int q = 0; q < 2; ++q) {
      acc[t] = __builtin_amdgcn_mfma_f32_16x16x32_bf16(ah[q], wh[t][q], acc[t], 0, 0, 0);
      acc[t] = __builtin_amdgcn_mfma_f32_16x16x32_bf16(ah[q], wl[t][q], acc[t], 0, 0, 0);
      acc[t] = __builtin_amdgcn_mfma_f32_16x16x32_bf16(al[q], wh[t][q], acc[t], 0, 0, 0);
    }
  float dv[4];
  if (DINV_OUT) {
#pragma unroll
    for (int r = 0; r < 4; ++r) {
      int row = row0 + quad * 4 + r;
      dv[r] = (row < n) ? dinv[row] : 0.0f;
    }
  }
#pragma unroll
  for (int t = 0; t < 4; ++t)
#pragma unroll
    for (int r = 0; r < 4; ++r) {
      int row = row0 + quad * 4 + r;
      if (row < n) {
        float v = acc[t][r] + bv[t];
        if (RELU_OUT) v = fmaxf(v, 0.0f);
        if (DINV_OUT) v *= dv[r];
        size_t idx = (size_t)row * 64 + t * 16 + col;
        if (OUT_MODE == 0) {
          ((float*)out0)[idx] = v;
        } else if (OUT_MODE == 1) {
          ((unsigned short*)out0)[idx] = f2bf_rne(v);
        } else {
          short hi, lo;
          split_bf(v, hi, lo);
          ((unsigned short*)out0)[idx] = (unsigned short)hi;
          ((unsigned short*)out1)[idx] = (unsigned short)lo;
        }
      }
    }
}

// One wave per node; 4 edge-slots x 16 lanes x 4 bf16 (8 B); 2x unrolled.
// out = relu(dinv[node]*(sum_src hws[src] + hws[node]) + bias), stored as
// hi/lo bf16 planes (split here, off the mm critical path).
__global__ void k_agg(const unsigned short* __restrict__ hws, const float* __restrict__ dinv,
                      const int* __restrict__ row_ptr, const int* __restrict__ srcs,
                      const float* __restrict__ bias, unsigned short* __restrict__ ohp,
                      unsigned short* __restrict__ olp, int n) {
  int wid = (blockIdx.x * blockDim.x + threadIdx.x) >> 6;
  if (wid >= n) return;
  int lane = threadIdx.x & 63;
  int slot = lane >> 4;  // 0..3
  int fg = lane & 15;    // 4-bf16 feature group
  const uint2* hw2 = (const uint2*)hws;  // row = 16 x uint2

  int p0 = row_ptr[wid], p1 = row_ptr[wid + 1];
  float4 acc = make_float4(0.f, 0.f, 0.f, 0.f);
  int p = p0 + slot;
  while (p + 4 < p1) {
    int s0 = srcs[p];
    int s1 = srcs[p + 4];
    uint2 u0 = hw2[(size_t)s0 * 16 + fg];
    uint2 u1 = hw2[(size_t)s1 * 16 + fg];
    float4 v0 = bf4_to_f4(u0);
    float4 v1 = bf4_to_f4(u1);
    acc.x += v0.x + v1.x;
    acc.y += v0.y + v1.y;
    acc.z += v0.z + v1.z;
    acc.w += v0.w + v1.w;
    p += 8;
  }
  if (p < p1) {
    float4 v = bf4_to_f4(hw2[(size_t)srcs[p] * 16 + fg]);
    acc.x += v.x; acc.y += v.y; acc.z += v.z; acc.w += v.w;
  }
#pragma unroll
  for (int off = 16; off < 64; off <<= 1) {
    acc.x += __shfl_xor(acc.x, off);
    acc.y += __shfl_xor(acc.y, off);
    acc.z += __shfl_xor(acc.z, off);
    acc.w += __shfl_xor(acc.w, off);
  }
  if (slot == 0) {
    float di = dinv[wid];
    float4 selfv = bf4_to_f4(hw2[(size_t)wid * 16 + fg]);
    float4 b4 = ((const float4*)bias)[fg];
    float r0 = fmaxf(fmaf(di, acc.x + selfv.x, b4.x), 0.f);
    float r1 = fmaxf(fmaf(di, acc.y + selfv.y, b4.y), 0.f);
    float r2 = fmaxf(fmaf(di, acc.z + selfv.z, b4.z), 0.f);
    float r3 = fmaxf(fmaf(di, acc.w + selfv.w, b4.w), 0.f);
    short h0, l0, h1, l1, h2, l2, h3, l3;
    split_bf(r0, h0, l0);
    split_bf(r1, h1, l1);
    split_bf(r2, h2, l2);
    split_bf(r3, h3, l3);
    uint2 hp, lp;
    hp.x = (unsigned short)h0 | ((unsigned)(unsigned short)h1 << 16);
    hp.y = (unsigned short)h2 | ((unsigned)(unsigned short)h3 << 16);
    lp.x = (unsigned short)l0 | ((unsigned)(unsigned short)l1 << 16);
    lp.y = (unsigned short)l2 | ((unsigned)(unsigned short)l3 << 16);
    ((uint2*)ohp)[(size_t)wid * 16 + fg] = hp;
    ((uint2*)olp)[(size_t)wid * 16 + fg] = lp;
  }
}

extern "C" void kernel_launch(void* const* d_in, const int* in_sizes, int n_in,
                              void* d_out, int out_size, void* d_ws, size_t ws_size,
                              hipStream_t stream) {
  const float* x = (const float*)d_in[0];
  const int* ei = (const int*)d_in[1];  // int32 per harness convention
  const float* W1 = (const float*)d_in[2];
  const float* b1 = (const float*)d_in[3];
  const float* W2 = (const float*)d_in[4];
  const float* b2 = (const float*)d_in[5];
  const float* W3 = (const float*)d_in[6];
  const float* b3 = (const float*)d_in[7];
  const float* fw1 = (const float*)d_in[8];
  const float* fb1 = (const float*)d_in[9];
  const float* fw2 = (const float*)d_in[10];
  const float* fb2 = (const float*)d_in[11];
  float* out = (float*)d_out;

  const int N = in_sizes[0] / 64;
  const int E = in_sizes[1] / 2;

  // workspace (~45 MB)
  char* w = (char*)d_ws;
  auto take = [&](size_t bytes) -> char* {
    char* p = w;
    w += (bytes + 255) & ~(size_t)255;
    return p;
  };
  float* dinv = (float*)take((size_t)N * 4);
  int* cursors = (int*)take((size_t)N * 4);
  int* row_ptr = (int*)take((size_t)(N + 1) * 4);
  int* bsums = (int*)take((size_t)SCAN_B * 4);
  int* srcs = (int*)take((size_t)E * 4);
  bf16x8* wpack = (bf16x8*)take((size_t)5 * 1024 * 16);              // 80 KB
  unsigned short* hws = (unsigned short*)take((size_t)N * 64 * 2);   // 12.8 MB
  unsigned short* hpl = (unsigned short*)take((size_t)N * 64 * 2);   // 12.8 MB
  unsigned short* lpl = (unsigned short*)take((size_t)N * 64 * 2);   // 12.8 MB

  const int B = 256;
  const int nb_scan = CDIV(N, SCAN_B);

  // ---- weight prep + CSR build ----
  k_prep<<<5, 512, 0, stream>>>(W1, W2, W3, fw1, fw2, wpack);
  k_zero_i32<<<CDIV(N, B), B, 0, stream>>>(cursors, N);  // counts
  k_count<<<CDIV(E, B), B, 0, stream>>>(ei, cursors, E);
  k_scan1<<<nb_scan, SCAN_B, 0, stream>>>(cursors, row_ptr, bsums, dinv, N);
  k_scan2<<<1, SCAN_B, 0, stream>>>(bsums, nb_scan);
  k_scan3<<<CDIV(N, B), B, 0, stream>>>(row_ptr, bsums, cursors, N, E);
  k_fill<<<4096, B, 0, stream>>>(ei, cursors, srcs, E, N);  // 8 XCD groups

  const int ntiles = CDIV(N, 16);
  const int MMG = CDIV(ntiles, 4);  // 1 tile/wave, 4 waves/block
  const int AGG_G = CDIV(N, 4);     // 1 node/wave

  // hws1 = bf16((x@W1)*dinv)   [fp32 in, split on the fly]
  k_mm<false, false, true, false, 1><<<MMG, B, 0, stream>>>(
      x, nullptr, nullptr, wpack + 0 * 1024, nullptr, dinv, hws, nullptr, N);
  // h1 = relu(dinv*(agg+self)+b1) -> planes
  k_agg<<<AGG_G, B, 0, stream>>>(hws, dinv, row_ptr, srcs, b1, hpl, lpl, N);
  // hws2 = bf16((h1@W2)*dinv)
  k_mm<false, false, true, true, 1><<<MMG, B, 0, stream>>>(
      nullptr, hpl, lpl, wpack + 1 * 1024, nullptr, dinv, hws, nullptr, N);
  // h2 -> planes (h1 consumed)
  k_agg<<<AGG_G, B, 0, stream>>>(hws, dinv, row_ptr, srcs, b2, hpl, lpl, N);
  // hws3 = bf16((h2@W3)*dinv)
  k_mm<false, false, true, true, 1><<<MMG, B, 0, stream>>>(
      nullptr, hpl, lpl, wpack + 2 * 1024, nullptr, dinv, hws, nullptr, N);
  // h3 -> planes
  k_agg<<<AGG_G, B, 0, stream>>>(hws, dinv, row_ptr, srcs, b3, hpl, lpl, N);
  // h4 = relu(h3@fw1+fb1) -> planes (in-place, wave-disjoint tiles)
  k_mm<true, true, false, true, 2><<<MMG, B, 0, stream>>>(
      nullptr, hpl, lpl, wpack + 3 * 1024, fb1, nullptr, hpl, lpl, N);
  // out = h4@fw2 + fb2 -> fp32 d_out
  k_mm<true, false, false, true, 0><<<MMG, B, 0, stream>>>(
      nullptr, hpl, lpl, wpack + 4 * 1024, fb2, nullptr, out, nullptr, N);
}

// Round 11
// 374.144 us; speedup vs baseline: 1.0361x; 1.0361x over previous
//
#include <hip/hip_runtime.h>
#include <cstdint>
#include <cstddef>

// GCN link prediction: 3x GCNConv(64->64) + ReLU, then 2-layer MLP head.
// N=100k, E=1M, dims 64. Round 11 = round-9 datapath (fp32 activations,
// packed-bf16 gather table, split-bf16 MFMA) + k_fill with 4 dst-ranges
// (blockIdx&3): 2-XCD line sharing instead of 8, duty cycle 1/4 instead of
// 1/8. Round-10's hi/lo planes + nontemporal loads reverted (regressed).

#define CDIV(a, b) (((a) + (b) - 1) / (b))
static constexpr int SCAN_B = 1024;

typedef __attribute__((ext_vector_type(8))) short bf16x8;
typedef __attribute__((ext_vector_type(4))) float f32x4;

// Split a into hi (RNE bf16) + lo (truncated bf16 of exact residual).
__device__ __forceinline__ void split_bf(float a, short& hi, short& lo) {
  unsigned u = __float_as_uint(a);
  unsigned r = u + (0x7FFF + ((u >> 16) & 1));  // RNE round to bf16
  hi = (short)(r >> 16);
  float hirec = __uint_as_float(r & 0xFFFF0000u);
  float res = a - hirec;  // exact
  lo = (short)(__float_as_uint(res) >> 16);  // truncate
}

__device__ __forceinline__ unsigned short f2bf_rne(float a) {
  unsigned u = __float_as_uint(a);
  u += 0x7FFF + ((u >> 16) & 1);
  return (unsigned short)(u >> 16);
}

__device__ __forceinline__ float4 bf4_to_f4(uint2 u) {
  float4 v;
  v.x = __uint_as_float(u.x << 16);
  v.y = __uint_as_float(u.x & 0xFFFF0000u);
  v.z = __uint_as_float(u.y << 16);
  v.w = __uint_as_float(u.y & 0xFFFF0000u);
  return v;
}

__global__ void k_zero_i32(int* __restrict__ p, int n) {
  int i = blockIdx.x * blockDim.x + threadIdx.x;
  if (i < n) p[i] = 0;
}

__global__ void k_count(const int* __restrict__ ei, int* __restrict__ counts, int E) {
  int e = blockIdx.x * blockDim.x + threadIdx.x;
  if (e < E) atomicAdd(&counts[ei[E + e]], 1);
}

// Inclusive block scan -> exclusive output + per-block sums; also dinv.
__global__ void k_scan1(const int* __restrict__ counts, int* __restrict__ excl,
                        int* __restrict__ bsums, float* __restrict__ dinv, int n) {
  __shared__ int sh[SCAN_B];
  int t = threadIdx.x;
  int idx = blockIdx.x * SCAN_B + t;
  int v = (idx < n) ? counts[idx] : 0;
  if (idx < n) dinv[idx] = rsqrtf((float)v + 1.0f);
  int val = v;
  sh[t] = val;
  __syncthreads();
  for (int off = 1; off < SCAN_B; off <<= 1) {
    int add = (t >= off) ? sh[t - off] : 0;
    __syncthreads();
    val += add;
    sh[t] = val;
    __syncthreads();
  }
  if (idx < n) excl[idx] = val - v;
  if (t == SCAN_B - 1) bsums[blockIdx.x] = val;
}

__global__ void k_scan2(int* __restrict__ bsums, int nb) {
  __shared__ int sh[SCAN_B];
  int t = threadIdx.x;
  int v = (t < nb) ? bsums[t] : 0;
  int val = v;
  sh[t] = val;
  __syncthreads();
  for (int off = 1; off < SCAN_B; off <<= 1) {
    int add = (t >= off) ? sh[t - off] : 0;
    __syncthreads();
    val += add;
    sh[t] = val;
    __syncthreads();
  }
  if (t < nb) bsums[t] = val - v;
}

// Finalize row_ptr; init fill cursors to row_ptr.
__global__ void k_scan3(int* __restrict__ row_ptr, const int* __restrict__ bsums,
                        int* __restrict__ cursors, int n, int E) {
  int i = blockIdx.x * blockDim.x + threadIdx.x;
  if (i < n) {
    int rp = row_ptr[i] + bsums[i >> 10];  // SCAN_B == 1024
    row_ptr[i] = rp;
    cursors[i] = rp;
  }
  if (i == 0) row_ptr[n] = E;
}

// Scatter src ids into dst-sorted order. 4 dst-range groups (blockIdx&3):
// each srcs line is written by at most 2 XCDs (round-robin heuristic), with
// 1/4 lane duty and 4 sweeps of the dst stream (vs 8 groups: 1-XCD lines
// but 1/8 duty and 8 sweeps — measured slower overall tradeoff).
__global__ void k_fill(const int* __restrict__ ei, int* __restrict__ cursors,
                       int* __restrict__ srcs, int E, int N) {
  int g = blockIdx.x & 3;
  int bi = blockIdx.x >> 2;
  int stride = (gridDim.x >> 2) * blockDim.x;
  int lo = (int)(((long long)N * g) >> 2);
  int hi = (int)(((long long)N * (g + 1)) >> 2);
  for (int e = bi * blockDim.x + threadIdx.x; e < E; e += stride) {
    int d = ei[E + e];
    if (d >= lo && d < hi) {
      int s = ei[e];
      int pos = atomicAdd(&cursors[d], 1);
      srcs[pos] = s;
    }
  }
}

// Pre-split 5 weight matrices (64x64, [in,out] row-major) into hi/lo bf16
// fragments, packed: packed[mat*1024 + ((t*2+q)*2+h)*64 + lane].
__global__ void k_prep(const float* __restrict__ w0, const float* __restrict__ w1,
                       const float* __restrict__ w2, const float* __restrict__ w3,
                       const float* __restrict__ w4, bf16x8* __restrict__ packed) {
  const float* W;
  switch (blockIdx.x) {
    case 0: W = w0; break;
    case 1: W = w1; break;
    case 2: W = w2; break;
    case 3: W = w3; break;
    default: W = w4; break;
  }
  int tid = threadIdx.x;  // 0..511
  int lane = tid & 63;
  int q = (tid >> 6) & 1;
  int t = tid >> 7;
  int col = lane & 15, quad = lane >> 4;
  bf16x8 hi8, lo8;
#pragma unroll
  for (int j = 0; j < 8; ++j) {
    int k = q * 32 + quad * 8 + j;
    short hi, lo;
    split_bf(W[k * 64 + t * 16 + col], hi, lo);
    hi8[j] = hi;
    lo8[j] = lo;
  }
  size_t base = (size_t)blockIdx.x * 1024 + ((t * 2 + q) * 2) * 64 + lane;
  packed[base] = hi8;
  packed[base + 64] = lo8;
}

// C[n x 64] = A @ W (+bias) (+relu) (optionally *dinv[row]); output fp32 or
// packed RNE bf16 (gather-table producer). One 16-row tile per wave.
// Verified layouts: A[m=lane&15][k=quad*8+j]; B[k][n=lane&15];
// C col=lane&15, row=quad*4+reg.
template <bool HAS_BIAS, bool RELU_OUT, bool DINV_OUT, bool BF16_OUT>
__global__ __launch_bounds__(256, 4)
void k_mm(const float* __restrict__ in, const bf16x8* __restrict__ Wp,
          const float* __restrict__ bias, const float* __restrict__ dinv,
          void* __restrict__ out, int n) {
  int lane = threadIdx.x & 63;
  int col = lane & 15, quad = lane >> 4;
  int tile = (blockIdx.x * blockDim.x + threadIdx.x) >> 6;
  int ntiles = (n + 15) >> 4;
  if (tile >= ntiles) return;

  bf16x8 wh[4][2], wl[4][2];
#pragma unroll
  for (int t = 0; t < 4; ++t)
#pragma unroll
    for (int q = 0; q < 2; ++q) {
      wh[t][q] = Wp[((t * 2 + q) * 2) * 64 + lane];
      wl[t][q] = Wp[((t * 2 + q) * 2 + 1) * 64 + lane];
    }
  float bv[4];
#pragma unroll
  for (int t = 0; t < 4; ++t) bv[t] = HAS_BIAS ? bias[t * 16 + col] : 0.0f;

  int row0 = tile << 4;
  int ar = row0 + col;
  if (ar > n - 1) ar = n - 1;  // clamp; stores guarded
  const float4* arow = (const float4*)(in + (size_t)ar * 64 + quad * 8);
  float4 a0 = arow[0], a1 = arow[1], a2 = arow[8], a3 = arow[9];

  bf16x8 ah[2], al[2];
  {
    float av0[8] = {a0.x, a0.y, a0.z, a0.w, a1.x, a1.y, a1.z, a1.w};
    float av1[8] = {a2.x, a2.y, a2.z, a2.w, a3.x, a3.y, a3.z, a3.w};
#pragma unroll
    for (int j = 0; j < 8; ++j) {
      short hi, lo;
      split_bf(av0[j], hi, lo);
      ah[0][j] = hi; al[0][j] = lo;
      split_bf(av1[j], hi, lo);
      ah[1][j] = hi; al[1][j] = lo;
    }
  }
  f32x4 acc[4];
#pragma unroll
  for (int t = 0; t < 4; ++t) acc[t] = (f32x4){0.f, 0.f, 0.f, 0.f};
#pragma unroll
  for (int t = 0; t < 4; ++t)
#pragma unroll
    for (int q = 0; q < 2; ++q) {
      acc[t] = __builtin_amdgcn_mfma_f32_16x16x32_bf16(ah[q], wh[t][q], acc[t], 0, 0, 0);
      acc[t] = __builtin_amdgcn_mfma_f32_16x16x32_bf16(ah[q], wl[t][q], acc[t], 0, 0, 0);
      acc[t] = __builtin_amdgcn_mfma_f32_16x16x32_bf16(al[q], wh[t][q], acc[t], 0, 0, 0);
    }
  float dv[4];
  if (DINV_OUT) {
#pragma unroll
    for (int r = 0; r < 4; ++r) {
      int row = row0 + quad * 4 + r;
      dv[r] = (row < n) ? dinv[row] : 0.0f;
    }
  }
#pragma unroll
  for (int t = 0; t < 4; ++t)
#pragma unroll
    for (int r = 0; r < 4; ++r) {
      int row = row0 + quad * 4 + r;
      if (row < n) {
        float v = acc[t][r] + bv[t];
        if (RELU_OUT) v = fmaxf(v, 0.0f);
        if (DINV_OUT) v *= dv[r];
        if (BF16_OUT) {
          ((unsigned short*)out)[(size_t)row * 64 + t * 16 + col] = f2bf_rne(v);
        } else {
          ((float*)out)[(size_t)row * 64 + t * 16 + col] = v;
        }
      }
    }
}

// One wave per node; 4 edge-slots x 16 lanes x 4 bf16 (8 B); 2x unrolled so
// 8 independent 128 B row gathers are in flight per wave.
// out = relu(dinv[node] * (sum_src hws[src] + hws[node]) + bias), fp32.
__global__ void k_agg(const unsigned short* __restrict__ hws, const float* __restrict__ dinv,
                      const int* __restrict__ row_ptr, const int* __restrict__ srcs,
                      const float* __restrict__ bias, float* __restrict__ out, int n) {
  int wid = (blockIdx.x * blockDim.x + threadIdx.x) >> 6;
  if (wid >= n) return;
  int lane = threadIdx.x & 63;
  int slot = lane >> 4;  // 0..3
  int fg = lane & 15;    // 4-bf16 feature group
  const uint2* hw2 = (const uint2*)hws;  // row = 16 x uint2

  int p0 = row_ptr[wid], p1 = row_ptr[wid + 1];
  float4 acc = make_float4(0.f, 0.f, 0.f, 0.f);
  int p = p0 + slot;
  while (p + 4 < p1) {
    int s0 = srcs[p];
    int s1 = srcs[p + 4];
    uint2 u0 = hw2[(size_t)s0 * 16 + fg];
    uint2 u1 = hw2[(size_t)s1 * 16 + fg];
    float4 v0 = bf4_to_f4(u0);
    float4 v1 = bf4_to_f4(u1);
    acc.x += v0.x + v1.x;
    acc.y += v0.y + v1.y;
    acc.z += v0.z + v1.z;
    acc.w += v0.w + v1.w;
    p += 8;
  }
  if (p < p1) {
    float4 v = bf4_to_f4(hw2[(size_t)srcs[p] * 16 + fg]);
    acc.x += v.x; acc.y += v.y; acc.z += v.z; acc.w += v.w;
  }
#pragma unroll
  for (int off = 16; off < 64; off <<= 1) {
    acc.x += __shfl_xor(acc.x, off);
    acc.y += __shfl_xor(acc.y, off);
    acc.z += __shfl_xor(acc.z, off);
    acc.w += __shfl_xor(acc.w, off);
  }
  if (slot == 0) {
    float di = dinv[wid];
    float4 selfv = bf4_to_f4(hw2[(size_t)wid * 16 + fg]);
    float4 b4 = ((const float4*)bias)[fg];
    float4 r;
    r.x = fmaxf(fmaf(di, acc.x + selfv.x, b4.x), 0.f);
    r.y = fmaxf(fmaf(di, acc.y + selfv.y, b4.y), 0.f);
    r.z = fmaxf(fmaf(di, acc.z + selfv.z, b4.z), 0.f);
    r.w = fmaxf(fmaf(di, acc.w + selfv.w, b4.w), 0.f);
    ((float4*)out)[(size_t)wid * 16 + fg] = r;
  }
}

extern "C" void kernel_launch(void* const* d_in, const int* in_sizes, int n_in,
                              void* d_out, int out_size, void* d_ws, size_t ws_size,
                              hipStream_t stream) {
  const float* x = (const float*)d_in[0];
  const int* ei = (const int*)d_in[1];  // int32 per harness convention
  const float* W1 = (const float*)d_in[2];
  const float* b1 = (const float*)d_in[3];
  const float* W2 = (const float*)d_in[4];
  const float* b2 = (const float*)d_in[5];
  const float* W3 = (const float*)d_in[6];
  const float* b3 = (const float*)d_in[7];
  const float* fw1 = (const float*)d_in[8];
  const float* fb1 = (const float*)d_in[9];
  const float* fw2 = (const float*)d_in[10];
  const float* fb2 = (const float*)d_in[11];
  float* out = (float*)d_out;

  const int N = in_sizes[0] / 64;
  const int E = in_sizes[1] / 2;

  // workspace (~44 MB); d_out doubles as an fp32 activation buffer
  char* w = (char*)d_ws;
  auto take = [&](size_t bytes) -> char* {
    char* p = w;
    w += (bytes + 255) & ~(size_t)255;
    return p;
  };
  float* dinv = (float*)take((size_t)N * 4);
  int* cursors = (int*)take((size_t)N * 4);
  int* row_ptr = (int*)take((size_t)(N + 1) * 4);
  int* bsums = (int*)take((size_t)SCAN_B * 4);
  int* srcs = (int*)take((size_t)E * 4);
  bf16x8* wpack = (bf16x8*)take((size_t)5 * 1024 * 16);             // 80 KB
  unsigned short* hws = (unsigned short*)take((size_t)N * 64 * 2);  // 12.8 MB
  float* buf0 = (float*)take((size_t)N * 64 * 4);                   // 25.6 MB
  float* buf1 = out;  // fully overwritten by the final mm

  const int B = 256;
  const int nb_scan = CDIV(N, SCAN_B);

  // ---- weight prep + CSR build ----
  k_prep<<<5, 512, 0, stream>>>(W1, W2, W3, fw1, fw2, wpack);
  k_zero_i32<<<CDIV(N, B), B, 0, stream>>>(cursors, N);  // counts
  k_count<<<CDIV(E, B), B, 0, stream>>>(ei, cursors, E);
  k_scan1<<<nb_scan, SCAN_B, 0, stream>>>(cursors, row_ptr, bsums, dinv, N);
  k_scan2<<<1, SCAN_B, 0, stream>>>(bsums, nb_scan);
  k_scan3<<<CDIV(N, B), B, 0, stream>>>(row_ptr, bsums, cursors, N, E);
  k_fill<<<4096, B, 0, stream>>>(ei, cursors, srcs, E, N);  // 4 dst-ranges

  const int ntiles = CDIV(N, 16);
  const int MMG = CDIV(ntiles, 4);  // 1 tile/wave, 4 waves/block
  const int AGG_G = CDIV(N, 4);     // 1 node/wave

  // hws1 = bf16((x@W1)*dinv)
  k_mm<false, false, true, true><<<MMG, B, 0, stream>>>(x, wpack + 0 * 1024, nullptr, dinv, hws, N);
  // h1 = relu(dinv*(agg+self) + b1)  [fp32, d_out]
  k_agg<<<AGG_G, B, 0, stream>>>(hws, dinv, row_ptr, srcs, b1, buf1, N);
  // hws2 = bf16((h1@W2)*dinv)
  k_mm<false, false, true, true><<<MMG, B, 0, stream>>>(buf1, wpack + 1 * 1024, nullptr, dinv, hws, N);
  // h2 -> buf0
  k_agg<<<AGG_G, B, 0, stream>>>(hws, dinv, row_ptr, srcs, b2, buf0, N);
  // hws3 = bf16((h2@W3)*dinv)
  k_mm<false, false, true, true><<<MMG, B, 0, stream>>>(buf0, wpack + 2 * 1024, nullptr, dinv, hws, N);
  // h3 -> d_out
  k_agg<<<AGG_G, B, 0, stream>>>(hws, dinv, row_ptr, srcs, b3, buf1, N);
  // h4 = relu(h3@fw1 + fb1) -> buf0 [fp32]
  k_mm<true, true, false, false><<<MMG, B, 0, stream>>>(buf1, wpack + 3 * 1024, fb1, nullptr, buf0, N);
  // out = h4@fw2 + fb2 -> d_out [fp32]
  k_mm<true, false, false, false><<<MMG, B, 0, stream>>>(buf0, wpack + 4 * 1024, fb2, nullptr, out, N);
}